// Round 1
// baseline (633.392 us; speedup 1.0000x reference)
//
#include <hip/hip_runtime.h>
#include <math.h>

// Problem constants (match reference)
#define BATCH 512
#define NROWS 1024
#define DDIM  256
#define NWAVES 8     // 512 threads = 8 waves of 64
#define RPW   128    // rows per wave: two 64-row ballot groups
#define RB    8      // rows per pipeline batch (stage depth)

// R4: 512-thread blocks (8 waves). A 1024-thread block forces 4 waves/SIMD
// and therefore a hard 128-VGPR cap -- the xA/xB double buffer (64 VGPRs)
// plus live state exceeds that, risking scratch spills of the hot staging
// data. 512 threads -> __launch_bounds__(512,2) -> 256-VGPR budget, zero
// spill. Each wave now owns 128 rows (two 64-bit ballot masks) and the slot
// extraction is fully BRANCHLESS (cndmask selects, no exec-mask regions),
// so each batch's 8 float4 loads are emitted as one straight-line cluster.
// Masked rows are never fetched; drained-mask slots re-load a resident row
// (L1 hit) and are excluded via the valid bitmask (score = -inf -> p = 0).

__device__ __forceinline__ unsigned extract_issue(
    unsigned long long& m0, unsigned long long& m1,
    const float4* __restrict__ nodeb,
    int rowbase, int lane, float4 x[RB])
{
    unsigned valid = 0;
    #pragma unroll
    for (int j = 0; j < RB; ++j) {
        const bool h0 = (m0 != 0ULL);                 // take from group 0 first
        const unsigned long long cur = h0 ? m0 : m1;
        const bool any = (cur != 0ULL);
        const int  r   = __ffsll(cur) - 1;            // -1 when cur == 0
        const int  row = (h0 ? 0 : 64) + (any ? r : 0);
        const unsigned long long nxt = cur & (cur - 1ULL);
        m0 = h0 ? nxt : m0;
        m1 = h0 ? m1  : nxt;
        valid |= any ? (1u << j) : 0u;
        // Unconditional load: whole wave reads one row, 64 lanes x 16B = 1KB.
        x[j] = nodeb[(size_t)(rowbase + row) * (DDIM / 4) + lane];
    }
    return valid;
}

__device__ __forceinline__ void consume(
    unsigned valid, const float4 x[RB], const float4 q,
    float& m, float& l, float4& o)
{
    float s[RB];
    #pragma unroll
    for (int j = 0; j < RB; ++j)
        s[j] = (valid & (1u << j))
             ? fmaf(x[j].x, q.x, fmaf(x[j].y, q.y, fmaf(x[j].z, q.z, x[j].w * q.w)))
             : -INFINITY;                 // stays -inf through the reduce

    #pragma unroll
    for (int off = 32; off > 0; off >>= 1) {
        #pragma unroll
        for (int j = 0; j < RB; ++j)
            s[j] += __shfl_xor(s[j], off);
    }

    float mnew = m;
    #pragma unroll
    for (int j = 0; j < RB; ++j) mnew = fmaxf(mnew, s[j]);   // >=1 finite s

    const float scale = __expf(m - mnew);   // first call: exp(-inf)=0
    float p[RB], psum = 0.f;
    #pragma unroll
    for (int j = 0; j < RB; ++j) { p[j] = __expf(s[j] - mnew); psum += p[j]; }

    l = l * scale + psum;
    o.x *= scale; o.y *= scale; o.z *= scale; o.w *= scale;
    #pragma unroll
    for (int j = 0; j < RB; ++j) {
        o.x = fmaf(p[j], x[j].x, o.x);    // p[j]=0 for invalid slots
        o.y = fmaf(p[j], x[j].y, o.y);
        o.z = fmaf(p[j], x[j].z, o.z);
        o.w = fmaf(p[j], x[j].w, o.w);
    }
    m = mnew;
}

__global__ __launch_bounds__(512, 2) void attn_pool_kernel(
    const float* __restrict__ node,   // [B, N, D]
    const int*   __restrict__ edge,   // [B, N]
    const int*   __restrict__ label,  // [B]
    const float* __restrict__ rel,    // [R, D]
    float*       __restrict__ out)    // [B, D]
{
    const int b    = blockIdx.x;
    const int tid  = threadIdx.x;
    const int lane = tid & 63;
    const int wave = tid >> 6;

    const int lab = label[b];
    const float4 q = *(const float4*)(rel + (size_t)lab * DDIM + lane * 4);

    const float4* nodeb = (const float4*)(node + (size_t)b * NROWS * DDIM);
    const int rowbase = wave * RPW;

    const int* edgeb = edge + (size_t)b * NROWS + rowbase;
    unsigned long long m0 = __ballot(edgeb[lane]      == 1);  // rows [rowbase, +64)
    unsigned long long m1 = __ballot(edgeb[64 + lane] == 1);  // rows [rowbase+64, +64)

    float  m = -INFINITY;
    float  l = 0.0f;
    float4 o = make_float4(0.f, 0.f, 0.f, 0.f);

    float4 xA[RB], xB[RB];
    unsigned vA = extract_issue(m0, m1, nodeb, rowbase, lane, xA);
    while (vA) {
        const unsigned vB = extract_issue(m0, m1, nodeb, rowbase, lane, xB);
        consume(vA, xA, q, m, l, o);          // B's loads in flight meanwhile
        if (!vB) break;
        vA = extract_issue(m0, m1, nodeb, rowbase, lane, xA);
        consume(vB, xB, q, m, l, o);          // A's loads in flight meanwhile
    }

    // ---- cross-wave merge via LDS ----
    __shared__ float s_m[NWAVES];
    __shared__ float s_l[NWAVES];
    __shared__ float s_o[NWAVES][DDIM];   // 8 KB

    if (lane == 0) { s_m[wave] = m; s_l[wave] = l; }   // wave-uniform after reduce
    *(float4*)&s_o[wave][lane * 4] = o;
    __syncthreads();

    if (tid < DDIM) {
        float M = -INFINITY;
        #pragma unroll
        for (int w = 0; w < NWAVES; ++w) M = fmaxf(M, s_m[w]);
        float L = 0.f, acc = 0.f;
        #pragma unroll
        for (int w = 0; w < NWAVES; ++w) {
            const float sc = __expf(s_m[w] - M);   // empty wave: exp(-inf)=0
            L   += s_l[w] * sc;
            acc += s_o[w][tid] * sc;
        }
        out[(size_t)b * DDIM + tid] = acc / L;
    }
}

extern "C" void kernel_launch(void* const* d_in, const int* in_sizes, int n_in,
                              void* d_out, int out_size, void* d_ws, size_t ws_size,
                              hipStream_t stream) {
    const float* node  = (const float*)d_in[0];  // [B,N,D] fp32
    const int*   edge  = (const int*)  d_in[1];  // [B,N]
    const int*   label = (const int*)  d_in[2];  // [B]
    const float* rel   = (const float*)d_in[3];  // [R,D]
    float*       out   = (float*)d_out;          // [B,D]

    attn_pool_kernel<<<dim3(BATCH), dim3(512), 0, stream>>>(node, edge, label, rel, out);
}